// Round 4
// baseline (611.949 us; speedup 1.0000x reference)
//
#include <hip/hip_runtime.h>
#include <hip/hip_bf16.h>

#define N_USERS   100000
#define N_ITEMS   50000
#define N_TOTAL   150000
#define DIM       64
#define NNZ       4000000
#define BATCH     8192

#define NB        587                      // ceil(150000 / 256) buckets of 256 rows
#define PB        512                      // pass A/B blocks
#define CHUNK     ((NNZ + PB - 1) / PB)    // 7813 edges per block

// bf16 helpers (manual RNE round; unpack via shift)
__device__ __forceinline__ unsigned f2bf_bits(float f) {
    unsigned u = __float_as_uint(f);
    return (u + 0x7FFFu + ((u >> 16) & 1u)) >> 16;
}
__device__ __forceinline__ float bf2f_lo(unsigned w) { return __uint_as_float(w << 16); }
__device__ __forceinline__ float bf2f_hi(unsigned w) { return __uint_as_float(w & 0xFFFF0000u); }

// one nnz contribution: packed (col,valbits) in 64b, gather lane's dim pair
__device__ __forceinline__ void nnz_fma(unsigned long long p,
                                        const unsigned short* __restrict__ x_in,
                                        int d2, float& s0, float& s1) {
    unsigned col = (unsigned)p;
    float v = __uint_as_float((unsigned)(p >> 32));
    unsigned xu = *(const unsigned*)(x_in + col * DIM + d2 * 2);
    s0 += v * bf2f_lo(xu);
    s1 += v * bf2f_hi(xu);
}

// ---------------------------------------------------------------------------
// Init: x_a = bf16(concat(user_emb, item_emb)); zero bucket totals
// ---------------------------------------------------------------------------
__global__ void k_init(const float* __restrict__ ue, const float* __restrict__ ie,
                       unsigned short* __restrict__ x, int* __restrict__ btotal) {
    int tid = blockIdx.x * blockDim.x + threadIdx.x;       // one per 4 elems
    const int tot4 = N_TOTAL * DIM / 4;
    if (tid < tot4) {
        const int uelems = N_USERS * DIM;
        int base = tid * 4;
        float4 v = (base < uelems) ? ((const float4*)ue)[tid]
                                   : ((const float4*)ie)[(base - uelems) / 4];
        ushort2 lo = make_ushort2((unsigned short)f2bf_bits(v.x), (unsigned short)f2bf_bits(v.y));
        ushort2 hi = make_ushort2((unsigned short)f2bf_bits(v.z), (unsigned short)f2bf_bits(v.w));
        ((ushort2*)x)[tid * 2]     = lo;
        ((ushort2*)x)[tid * 2 + 1] = hi;
    }
    if (tid < NB) btotal[tid] = 0;
}

// ---------------------------------------------------------------------------
// Pass A: per-block LDS bucket histogram; reserve per-(block,bucket) sub-range
// ---------------------------------------------------------------------------
__global__ void k_bcount(const int* __restrict__ rows, int* __restrict__ btotal,
                         int* __restrict__ myBase) {
    __shared__ int h[NB];
    for (int i = threadIdx.x; i < NB; i += 256) h[i] = 0;
    __syncthreads();
    int s = blockIdx.x * CHUNK;
    int e = s + CHUNK; if (e > NNZ) e = NNZ;
    for (int j = s + threadIdx.x; j < e; j += 256)
        atomicAdd(&h[rows[j] >> 8], 1);
    __syncthreads();
    for (int i = threadIdx.x; i < NB; i += 256) {
        int c = h[i];
        myBase[blockIdx.x * NB + i] = c ? atomicAdd(&btotal[i], c) : 0;
    }
}

// ---------------------------------------------------------------------------
// Serial exclusive scan of bucket totals (587 values - trivial)
// ---------------------------------------------------------------------------
__global__ void k_bscan(const int* __restrict__ btotal, int* __restrict__ bbase,
                        int* __restrict__ row_ptr) {
    if (threadIdx.x == 0) {
        int acc = 0;
        for (int i = 0; i < NB; ++i) {
            bbase[i] = acc;
            acc += btotal[i];
        }
        bbase[NB] = acc;            // == NNZ
        row_ptr[N_TOTAL] = acc;
    }
}

// ---------------------------------------------------------------------------
// Pass B: append edges into per-(block,bucket) reserved sub-ranges.
// Packed: (rowlow << 18) | col  (col < 2^18, rowlow < 2^8)
// ---------------------------------------------------------------------------
__global__ void k_bucket(const int* __restrict__ rows, const int* __restrict__ cols,
                         const float* __restrict__ vals, const int* __restrict__ bbase,
                         const int* __restrict__ myBase, uint2* __restrict__ bucketed) {
    __shared__ int cnt[NB];
    for (int i = threadIdx.x; i < NB; i += 256)
        cnt[i] = bbase[i] + myBase[blockIdx.x * NB + i];
    __syncthreads();
    int s = blockIdx.x * CHUNK;
    int e = s + CHUNK; if (e > NNZ) e = NNZ;
    for (int j = s + threadIdx.x; j < e; j += 256) {
        int r = rows[j];
        int bkt = r >> 8;
        int p = atomicAdd(&cnt[bkt], 1);
        unsigned long long packed = (unsigned long long)__float_as_uint(vals[j]) << 32
                                  | (((unsigned)(r & 255) << 18) | (unsigned)cols[j]);
        __builtin_nontemporal_store(packed, (unsigned long long*)(bucketed + p));
    }
}

// ---------------------------------------------------------------------------
// Pass C: one block per bucket. LDS row-hist -> block scan -> row_ptr,
// then L2-local scatter into final CSR (col, val) pairs.
// ---------------------------------------------------------------------------
__global__ void k_csr(const uint2* __restrict__ bucketed, const int* __restrict__ bbase,
                      uint2* __restrict__ pairs, int* __restrict__ row_ptr) {
    __shared__ int rc[256];
    __shared__ int sc[256];
    __shared__ int fillc[256];
    int b = blockIdx.x, t = threadIdx.x;
    int s = bbase[b], e = bbase[b + 1];
    rc[t] = 0;
    __syncthreads();
    for (int j = s + t; j < e; j += 256)
        atomicAdd(&rc[bucketed[j].x >> 18], 1);
    __syncthreads();
    sc[t] = rc[t];
    __syncthreads();
    for (int off = 1; off < 256; off <<= 1) {
        int v = (t >= off) ? sc[t - off] : 0;
        __syncthreads();
        sc[t] += v;
        __syncthreads();
    }
    int excl = sc[t] - rc[t];
    int base = s + excl;
    fillc[t] = base;
    int row = b * 256 + t;
    if (row < N_TOTAL) row_ptr[row] = base;
    __syncthreads();
    for (int j = s + t; j < e; j += 256) {
        uint2 pr = bucketed[j];
        int pos = atomicAdd(&fillc[pr.x >> 18], 1);
        unsigned long long packed = (unsigned long long)pr.y << 32 | (pr.x & 0x3FFFFu);
        __builtin_nontemporal_store(packed, (unsigned long long*)(pairs + pos));
    }
}

// ---------------------------------------------------------------------------
// SpMM (bf16 x): one wave per row; half-wave per nnz, lane holds bfloat162.
// 8 nnz per iteration -> 4 independent gather chains per lane.
// Pairs loaded nontemporal so the 32 MB stream doesn't evict x from L2.
// ---------------------------------------------------------------------------
__global__ void k_spmm(const int* __restrict__ row_ptr, const uint2* __restrict__ pairs,
                       const unsigned short* __restrict__ x_in,
                       unsigned short* __restrict__ x_out) {
    int gw   = (blockIdx.x * blockDim.x + threadIdx.x) >> 6;
    int lane = threadIdx.x & 63;
    if (gw >= N_TOTAL) return;
    int s = row_ptr[gw], e = row_ptr[gw + 1];
    int half = lane >> 5;          // which nnz of the pair
    int d2   = lane & 31;          // dim pair: dims 2*d2, 2*d2+1
    float a0 = 0.f, a1 = 0.f, b0 = 0.f, b1 = 0.f;
    float c0 = 0.f, c1 = 0.f, d0 = 0.f, d1 = 0.f;
    int j = s;
    for (; j + 8 <= e; j += 8) {
        const unsigned long long* pp = (const unsigned long long*)(pairs + j + half);
        unsigned long long p0 = __builtin_nontemporal_load(pp);
        unsigned long long p1 = __builtin_nontemporal_load(pp + 2);
        unsigned long long p2 = __builtin_nontemporal_load(pp + 4);
        unsigned long long p3 = __builtin_nontemporal_load(pp + 6);
        nnz_fma(p0, x_in, d2, a0, a1);
        nnz_fma(p1, x_in, d2, b0, b1);
        nnz_fma(p2, x_in, d2, c0, c1);
        nnz_fma(p3, x_in, d2, d0, d1);
    }
    for (; j + 2 <= e; j += 2) {
        unsigned long long p = __builtin_nontemporal_load(
            (const unsigned long long*)(pairs + j + half));
        nnz_fma(p, x_in, d2, a0, a1);
    }
    if (j < e && half == 0) {
        unsigned long long p = __builtin_nontemporal_load(
            (const unsigned long long*)(pairs + j));
        nnz_fma(p, x_in, d2, a0, a1);
    }
    float s0 = (a0 + b0) + (c0 + d0);
    float s1 = (a1 + b1) + (c1 + d1);
    s0 += __shfl_xor(s0, 32, 64);
    s1 += __shfl_xor(s1, 32, 64);
    if (half == 0) {
        unsigned w = f2bf_bits(s0) | (f2bf_bits(s1) << 16);
        *(unsigned*)(x_out + gw * DIM + d2 * 2) = w;
    }
}

// ---------------------------------------------------------------------------
// Last layer: SpMM for sampled rows only, accumulate fp32 into sacc.
// ---------------------------------------------------------------------------
__global__ void k_spmm_rows(const int* __restrict__ row_ptr, const uint2* __restrict__ pairs,
                            const unsigned short* __restrict__ x_in,
                            const int* __restrict__ users, const int* __restrict__ pos,
                            const int* __restrict__ neg, float* __restrict__ sacc) {
    int w    = (blockIdx.x * blockDim.x + threadIdx.x) >> 6;
    int lane = threadIdx.x & 63;
    if (w >= 3 * BATCH) return;
    int row;
    if (w < BATCH)          row = users[w];
    else if (w < 2 * BATCH) row = N_USERS + pos[w - BATCH];
    else                    row = N_USERS + neg[w - 2 * BATCH];
    int s = row_ptr[row], e = row_ptr[row + 1];
    int half = lane >> 5;
    int d2   = lane & 31;
    float a0 = 0.f, a1 = 0.f, b0 = 0.f, b1 = 0.f;
    float c0 = 0.f, c1 = 0.f, d0 = 0.f, d1 = 0.f;
    int j = s;
    for (; j + 8 <= e; j += 8) {
        const unsigned long long* pp = (const unsigned long long*)(pairs + j + half);
        unsigned long long p0 = __builtin_nontemporal_load(pp);
        unsigned long long p1 = __builtin_nontemporal_load(pp + 2);
        unsigned long long p2 = __builtin_nontemporal_load(pp + 4);
        unsigned long long p3 = __builtin_nontemporal_load(pp + 6);
        nnz_fma(p0, x_in, d2, a0, a1);
        nnz_fma(p1, x_in, d2, b0, b1);
        nnz_fma(p2, x_in, d2, c0, c1);
        nnz_fma(p3, x_in, d2, d0, d1);
    }
    for (; j + 2 <= e; j += 2) {
        unsigned long long p = __builtin_nontemporal_load(
            (const unsigned long long*)(pairs + j + half));
        nnz_fma(p, x_in, d2, a0, a1);
    }
    if (j < e && half == 0) {
        unsigned long long p = __builtin_nontemporal_load(
            (const unsigned long long*)(pairs + j));
        nnz_fma(p, x_in, d2, a0, a1);
    }
    float s0 = (a0 + b0) + (c0 + d0);
    float s1 = (a1 + b1) + (c1 + d1);
    s0 += __shfl_xor(s0, 32, 64);
    s1 += __shfl_xor(s1, 32, 64);
    if (half == 0) {
        float2* sp = (float2*)(sacc + w * DIM);
        float2 cur = sp[d2];
        cur.x += s0; cur.y += s1;
        sp[d2] = cur;
    }
}

// ---------------------------------------------------------------------------
// sacc init from the ORIGINAL fp32 embeddings (layer-0 term, exact)
// ---------------------------------------------------------------------------
__global__ void k_gacc_init(const int* __restrict__ users, const int* __restrict__ pos,
                            const int* __restrict__ neg, const float* __restrict__ ue,
                            const float* __restrict__ ie, float* __restrict__ sacc) {
    int tid = blockIdx.x * blockDim.x + threadIdx.x;
    int j = tid >> 6, lane = tid & 63;
    if (j >= 3 * BATCH) return;
    float v;
    if (j < BATCH)            v = ue[users[j] * DIM + lane];
    else if (j < 2 * BATCH)   v = ie[pos[j - BATCH] * DIM + lane];
    else                      v = ie[neg[j - 2 * BATCH] * DIM + lane];
    sacc[tid] = v;
}

// ---------------------------------------------------------------------------
// Accumulate sampled rows of a bf16 layer output into sacc
// ---------------------------------------------------------------------------
__global__ void k_gacc_add(const int* __restrict__ users, const int* __restrict__ pos,
                           const int* __restrict__ neg,
                           const unsigned short* __restrict__ x, float* __restrict__ sacc) {
    int tid = blockIdx.x * blockDim.x + threadIdx.x;
    int j = tid >> 6, lane = tid & 63;
    if (j >= 3 * BATCH) return;
    int row;
    if (j < BATCH)            row = users[j];
    else if (j < 2 * BATCH)   row = N_USERS + pos[j - BATCH];
    else                      row = N_USERS + neg[j - 2 * BATCH];
    unsigned short u = x[row * DIM + lane];
    sacc[tid] += __uint_as_float((unsigned)u << 16);
}

// ---------------------------------------------------------------------------
// Final: scores + raw layer-0 embeddings
// ---------------------------------------------------------------------------
__global__ void k_final(const float* __restrict__ sacc, const float* __restrict__ ue,
                        const float* __restrict__ ie, const int* __restrict__ users,
                        const int* __restrict__ pos, const int* __restrict__ neg,
                        float* __restrict__ out) {
    int tid = blockIdx.x * blockDim.x + threadIdx.x;
    int b = tid >> 6, lane = tid & 63;
    if (b >= BATCH) return;
    float ul = sacc[b * DIM + lane] * 0.25f;
    float pl = sacc[(BATCH + b) * DIM + lane] * 0.25f;
    float nl = sacc[(2 * BATCH + b) * DIM + lane] * 0.25f;
    float ps = ul * pl;
    float ns = ul * nl;
    for (int m = 1; m < 64; m <<= 1) {
        ps += __shfl_xor(ps, m, 64);
        ns += __shfl_xor(ns, m, 64);
    }
    if (lane == 0) {
        out[b] = ps;
        out[BATCH + b] = ns;
    }
    int u = users[b], p = pos[b], ng = neg[b];
    float* o = out + 2 * BATCH;
    o[b * DIM + lane]                   = ue[u * DIM + lane];
    o[BATCH * DIM + b * DIM + lane]     = ie[p * DIM + lane];
    o[2 * BATCH * DIM + b * DIM + lane] = ie[ng * DIM + lane];
}

// ---------------------------------------------------------------------------
extern "C" void kernel_launch(void* const* d_in, const int* in_sizes, int n_in,
                              void* d_out, int out_size, void* d_ws, size_t ws_size,
                              hipStream_t stream) {
    const float* user_emb = (const float*)d_in[0];
    const float* item_emb = (const float*)d_in[1];
    const float* adj_vals = (const float*)d_in[2];
    const int*   adj_rows = (const int*)d_in[3];
    const int*   adj_cols = (const int*)d_in[4];
    const int*   users    = (const int*)d_in[5];
    const int*   pos      = (const int*)d_in[6];
    const int*   neg      = (const int*)d_in[7];
    float* out = (float*)d_out;

    char* ws = (char*)d_ws;
    const size_t SZ_X = (size_t)N_TOTAL * DIM * 2;               // 19.2 MB (bf16)
    unsigned short* x_a = (unsigned short*)(ws);
    unsigned short* x_b = (unsigned short*)(ws + SZ_X);
    uint2* pairs    = (uint2*)(ws + 2 * SZ_X);
    uint2* bucketed = (uint2*)(ws + 2 * SZ_X + (size_t)NNZ * 8);
    char*  p3       = ws + 2 * SZ_X + 2 * (size_t)NNZ * 8;
    int*   row_ptr  = (int*)p3;                    // N_TOTAL + 1 (+pad)
    int*   btotal   = row_ptr + (N_TOTAL + 64);
    int*   bbase    = btotal + (NB + 64);          // NB + 1
    int*   myBase   = bbase + (NB + 64);           // PB * NB
    float* sacc     = (float*)(myBase + PB * NB + 64);

    const int TPB = 256;

    // 1) init x_a (bf16) + zero bucket totals
    k_init<<<(N_TOTAL * DIM / 4 + TPB - 1) / TPB, TPB, 0, stream>>>(user_emb, item_emb, x_a, btotal);
    // 2) CSR build: count -> scan -> bucket -> local scatter
    k_bcount<<<PB, TPB, 0, stream>>>(adj_rows, btotal, myBase);
    k_bscan<<<1, 64, 0, stream>>>(btotal, bbase, row_ptr);
    k_bucket<<<PB, TPB, 0, stream>>>(adj_rows, adj_cols, adj_vals, bbase, myBase, bucketed);
    k_csr<<<NB, TPB, 0, stream>>>(bucketed, bbase, pairs, row_ptr);

    // 3) sacc = layer-0 rows (exact fp32 from inputs)
    k_gacc_init<<<(3 * BATCH * DIM) / TPB, TPB, 0, stream>>>(users, pos, neg, user_emb, item_emb, sacc);

    // 4) layers 1,2 full; layer 3 sampled-rows only (fused accumulate)
    const int SPMM_BLOCKS = (N_TOTAL * 64 + TPB - 1) / TPB;
    k_spmm<<<SPMM_BLOCKS, TPB, 0, stream>>>(row_ptr, pairs, x_a, x_b);
    k_gacc_add<<<(3 * BATCH * DIM) / TPB, TPB, 0, stream>>>(users, pos, neg, x_b, sacc);
    k_spmm<<<SPMM_BLOCKS, TPB, 0, stream>>>(row_ptr, pairs, x_b, x_a);
    k_gacc_add<<<(3 * BATCH * DIM) / TPB, TPB, 0, stream>>>(users, pos, neg, x_a, sacc);
    k_spmm_rows<<<(3 * BATCH * 64) / TPB, TPB, 0, stream>>>(row_ptr, pairs, x_a, users, pos, neg, sacc);

    // 5) final outputs
    k_final<<<(BATCH * DIM) / TPB, TPB, 0, stream>>>(sacc, user_emb, item_emb, users, pos, neg, out);
}

// Round 5
// 460.978 us; speedup vs baseline: 1.3275x; 1.3275x over previous
//
#include <hip/hip_runtime.h>
#include <hip/hip_bf16.h>

#define N_USERS   100000
#define N_ITEMS   50000
#define N_TOTAL   150000
#define DIM       64
#define NNZ       4000000
#define BATCH     8192

#define NB        587                      // ceil(150000 / 256) buckets of 256 rows
#define PB        1024                     // pass A/B blocks
#define CHUNK     ((NNZ + PB - 1) / PB)    // 3907 edges per block

// bf16 helpers (manual RNE round; unpack via shift)
__device__ __forceinline__ unsigned f2bf_bits(float f) {
    unsigned u = __float_as_uint(f);
    return (u + 0x7FFFu + ((u >> 16) & 1u)) >> 16;
}
__device__ __forceinline__ float bf2f_lo(unsigned w) { return __uint_as_float(w << 16); }
__device__ __forceinline__ float bf2f_hi(unsigned w) { return __uint_as_float(w & 0xFFFF0000u); }

// one nnz contribution: packed (col,valbits) in 64b, gather lane's dim pair
__device__ __forceinline__ void nnz_fma(unsigned long long p,
                                        const unsigned short* __restrict__ x_in,
                                        int d2, float& s0, float& s1) {
    unsigned col = (unsigned)p;
    float v = __uint_as_float((unsigned)(p >> 32));
    unsigned xu = *(const unsigned*)(x_in + col * DIM + d2 * 2);
    s0 += v * bf2f_lo(xu);
    s1 += v * bf2f_hi(xu);
}

// ---------------------------------------------------------------------------
// Init: x_a = bf16(concat(user_emb, item_emb)); zero bucket totals
// ---------------------------------------------------------------------------
__global__ void k_init(const float* __restrict__ ue, const float* __restrict__ ie,
                       unsigned short* __restrict__ x, int* __restrict__ btotal) {
    int tid = blockIdx.x * blockDim.x + threadIdx.x;       // one per 4 elems
    const int tot4 = N_TOTAL * DIM / 4;
    if (tid < tot4) {
        const int uelems = N_USERS * DIM;
        int base = tid * 4;
        float4 v = (base < uelems) ? ((const float4*)ue)[tid]
                                   : ((const float4*)ie)[(base - uelems) / 4];
        ushort2 lo = make_ushort2((unsigned short)f2bf_bits(v.x), (unsigned short)f2bf_bits(v.y));
        ushort2 hi = make_ushort2((unsigned short)f2bf_bits(v.z), (unsigned short)f2bf_bits(v.w));
        ((ushort2*)x)[tid * 2]     = lo;
        ((ushort2*)x)[tid * 2 + 1] = hi;
    }
    if (tid < NB) btotal[tid] = 0;
}

// ---------------------------------------------------------------------------
// Pass A: per-block LDS bucket histogram; reserve per-(block,bucket) sub-range
// ---------------------------------------------------------------------------
__global__ void k_bcount(const int* __restrict__ rows, int* __restrict__ btotal,
                         int* __restrict__ myBase) {
    __shared__ int h[NB];
    for (int i = threadIdx.x; i < NB; i += 256) h[i] = 0;
    __syncthreads();
    int s = blockIdx.x * CHUNK;
    int e = s + CHUNK; if (e > NNZ) e = NNZ;
    for (int j = s + threadIdx.x; j < e; j += 256)
        atomicAdd(&h[rows[j] >> 8], 1);
    __syncthreads();
    for (int i = threadIdx.x; i < NB; i += 256) {
        int c = h[i];
        myBase[blockIdx.x * NB + i] = c ? atomicAdd(&btotal[i], c) : 0;
    }
}

// ---------------------------------------------------------------------------
// Serial exclusive scan of bucket totals (587 values - trivial)
// ---------------------------------------------------------------------------
__global__ void k_bscan(const int* __restrict__ btotal, int* __restrict__ bbase,
                        int* __restrict__ row_ptr) {
    if (threadIdx.x == 0) {
        int acc = 0;
        for (int i = 0; i < NB; ++i) {
            bbase[i] = acc;
            acc += btotal[i];
        }
        bbase[NB] = acc;            // == NNZ
        row_ptr[N_TOTAL] = acc;
    }
}

// ---------------------------------------------------------------------------
// Pass B: append edges into per-(block,bucket) reserved sub-ranges.
// Packed: (rowlow << 18) | col  (col < 2^18, rowlow < 2^8)
// Streaming inputs nt-loaded; scatter stores PLAIN so L2 write-combines.
// ---------------------------------------------------------------------------
__global__ void k_bucket(const int* __restrict__ rows, const int* __restrict__ cols,
                         const float* __restrict__ vals, const int* __restrict__ bbase,
                         const int* __restrict__ myBase, uint2* __restrict__ bucketed) {
    __shared__ int cnt[NB];
    for (int i = threadIdx.x; i < NB; i += 256)
        cnt[i] = bbase[i] + myBase[blockIdx.x * NB + i];
    __syncthreads();
    int s = blockIdx.x * CHUNK;
    int e = s + CHUNK; if (e > NNZ) e = NNZ;
    for (int j = s + threadIdx.x; j < e; j += 256) {
        int r = __builtin_nontemporal_load(rows + j);
        int c = __builtin_nontemporal_load(cols + j);
        float v = __builtin_nontemporal_load(vals + j);
        int bkt = r >> 8;
        int p = atomicAdd(&cnt[bkt], 1);
        bucketed[p] = make_uint2(((unsigned)(r & 255) << 18) | (unsigned)c,
                                 __float_as_uint(v));
    }
}

// ---------------------------------------------------------------------------
// Pass C: one 512-thread block per bucket. LDS row-hist -> scan -> row_ptr,
// then L2-local scatter into final CSR (col, val) pairs. Plain stores.
// ---------------------------------------------------------------------------
__global__ void k_csr(const uint2* __restrict__ bucketed, const int* __restrict__ bbase,
                      uint2* __restrict__ pairs, int* __restrict__ row_ptr) {
    __shared__ int rc[256];
    __shared__ int sc[256];
    __shared__ int fillc[256];
    int b = blockIdx.x, t = threadIdx.x;
    int s = bbase[b], e = bbase[b + 1];
    if (t < 256) rc[t] = 0;
    __syncthreads();
    for (int j = s + t; j < e; j += 512)
        atomicAdd(&rc[bucketed[j].x >> 18], 1);
    __syncthreads();
    if (t < 256) sc[t] = rc[t];
    __syncthreads();
    for (int off = 1; off < 256; off <<= 1) {
        int v = 0;
        if (t < 256 && t >= off) v = sc[t - off];
        __syncthreads();
        if (t < 256 && t >= off) sc[t] += v;
        __syncthreads();
    }
    if (t < 256) {
        int excl = sc[t] - rc[t];
        int base = s + excl;
        fillc[t] = base;
        int row = b * 256 + t;
        if (row < N_TOTAL) row_ptr[row] = base;
    }
    __syncthreads();
    for (int j = s + t; j < e; j += 512) {
        uint2 pr = bucketed[j];
        int pos = atomicAdd(&fillc[pr.x >> 18], 1);
        pairs[pos] = make_uint2(pr.x & 0x3FFFFu, pr.y);
    }
}

// ---------------------------------------------------------------------------
// SpMM (bf16 x): one wave per row; half-wave per nnz, lane holds bfloat162.
// 8 nnz per iteration -> 4 independent gather chains per lane.
// Pairs loaded nontemporal so the 32 MB stream doesn't evict x from L2.
// ---------------------------------------------------------------------------
__global__ void k_spmm(const int* __restrict__ row_ptr, const uint2* __restrict__ pairs,
                       const unsigned short* __restrict__ x_in,
                       unsigned short* __restrict__ x_out) {
    int gw   = (blockIdx.x * blockDim.x + threadIdx.x) >> 6;
    int lane = threadIdx.x & 63;
    if (gw >= N_TOTAL) return;
    int s = row_ptr[gw], e = row_ptr[gw + 1];
    int half = lane >> 5;          // which nnz of the pair
    int d2   = lane & 31;          // dim pair: dims 2*d2, 2*d2+1
    float a0 = 0.f, a1 = 0.f, b0 = 0.f, b1 = 0.f;
    float c0 = 0.f, c1 = 0.f, d0 = 0.f, d1 = 0.f;
    int j = s;
    for (; j + 8 <= e; j += 8) {
        const unsigned long long* pp = (const unsigned long long*)(pairs + j + half);
        unsigned long long p0 = __builtin_nontemporal_load(pp);
        unsigned long long p1 = __builtin_nontemporal_load(pp + 2);
        unsigned long long p2 = __builtin_nontemporal_load(pp + 4);
        unsigned long long p3 = __builtin_nontemporal_load(pp + 6);
        nnz_fma(p0, x_in, d2, a0, a1);
        nnz_fma(p1, x_in, d2, b0, b1);
        nnz_fma(p2, x_in, d2, c0, c1);
        nnz_fma(p3, x_in, d2, d0, d1);
    }
    for (; j + 2 <= e; j += 2) {
        unsigned long long p = __builtin_nontemporal_load(
            (const unsigned long long*)(pairs + j + half));
        nnz_fma(p, x_in, d2, a0, a1);
    }
    if (j < e && half == 0) {
        unsigned long long p = __builtin_nontemporal_load(
            (const unsigned long long*)(pairs + j));
        nnz_fma(p, x_in, d2, a0, a1);
    }
    float s0 = (a0 + b0) + (c0 + d0);
    float s1 = (a1 + b1) + (c1 + d1);
    s0 += __shfl_xor(s0, 32, 64);
    s1 += __shfl_xor(s1, 32, 64);
    if (half == 0) {
        unsigned w = f2bf_bits(s0) | (f2bf_bits(s1) << 16);
        *(unsigned*)(x_out + gw * DIM + d2 * 2) = w;
    }
}

// ---------------------------------------------------------------------------
// Last layer: SpMM for sampled rows only, accumulate fp32 into sacc.
// ---------------------------------------------------------------------------
__global__ void k_spmm_rows(const int* __restrict__ row_ptr, const uint2* __restrict__ pairs,
                            const unsigned short* __restrict__ x_in,
                            const int* __restrict__ users, const int* __restrict__ pos,
                            const int* __restrict__ neg, float* __restrict__ sacc) {
    int w    = (blockIdx.x * blockDim.x + threadIdx.x) >> 6;
    int lane = threadIdx.x & 63;
    if (w >= 3 * BATCH) return;
    int row;
    if (w < BATCH)          row = users[w];
    else if (w < 2 * BATCH) row = N_USERS + pos[w - BATCH];
    else                    row = N_USERS + neg[w - 2 * BATCH];
    int s = row_ptr[row], e = row_ptr[row + 1];
    int half = lane >> 5;
    int d2   = lane & 31;
    float a0 = 0.f, a1 = 0.f, b0 = 0.f, b1 = 0.f;
    float c0 = 0.f, c1 = 0.f, d0 = 0.f, d1 = 0.f;
    int j = s;
    for (; j + 8 <= e; j += 8) {
        const unsigned long long* pp = (const unsigned long long*)(pairs + j + half);
        unsigned long long p0 = __builtin_nontemporal_load(pp);
        unsigned long long p1 = __builtin_nontemporal_load(pp + 2);
        unsigned long long p2 = __builtin_nontemporal_load(pp + 4);
        unsigned long long p3 = __builtin_nontemporal_load(pp + 6);
        nnz_fma(p0, x_in, d2, a0, a1);
        nnz_fma(p1, x_in, d2, b0, b1);
        nnz_fma(p2, x_in, d2, c0, c1);
        nnz_fma(p3, x_in, d2, d0, d1);
    }
    for (; j + 2 <= e; j += 2) {
        unsigned long long p = __builtin_nontemporal_load(
            (const unsigned long long*)(pairs + j + half));
        nnz_fma(p, x_in, d2, a0, a1);
    }
    if (j < e && half == 0) {
        unsigned long long p = __builtin_nontemporal_load(
            (const unsigned long long*)(pairs + j));
        nnz_fma(p, x_in, d2, a0, a1);
    }
    float s0 = (a0 + b0) + (c0 + d0);
    float s1 = (a1 + b1) + (c1 + d1);
    s0 += __shfl_xor(s0, 32, 64);
    s1 += __shfl_xor(s1, 32, 64);
    if (half == 0) {
        float2* sp = (float2*)(sacc + w * DIM);
        float2 cur = sp[d2];
        cur.x += s0; cur.y += s1;
        sp[d2] = cur;
    }
}

// ---------------------------------------------------------------------------
// sacc init from the ORIGINAL fp32 embeddings (layer-0 term, exact)
// ---------------------------------------------------------------------------
__global__ void k_gacc_init(const int* __restrict__ users, const int* __restrict__ pos,
                            const int* __restrict__ neg, const float* __restrict__ ue,
                            const float* __restrict__ ie, float* __restrict__ sacc) {
    int tid = blockIdx.x * blockDim.x + threadIdx.x;
    int j = tid >> 6, lane = tid & 63;
    if (j >= 3 * BATCH) return;
    float v;
    if (j < BATCH)            v = ue[users[j] * DIM + lane];
    else if (j < 2 * BATCH)   v = ie[pos[j - BATCH] * DIM + lane];
    else                      v = ie[neg[j - 2 * BATCH] * DIM + lane];
    sacc[tid] = v;
}

// ---------------------------------------------------------------------------
// Accumulate sampled rows of a bf16 layer output into sacc
// ---------------------------------------------------------------------------
__global__ void k_gacc_add(const int* __restrict__ users, const int* __restrict__ pos,
                           const int* __restrict__ neg,
                           const unsigned short* __restrict__ x, float* __restrict__ sacc) {
    int tid = blockIdx.x * blockDim.x + threadIdx.x;
    int j = tid >> 6, lane = tid & 63;
    if (j >= 3 * BATCH) return;
    int row;
    if (j < BATCH)            row = users[j];
    else if (j < 2 * BATCH)   row = N_USERS + pos[j - BATCH];
    else                      row = N_USERS + neg[j - 2 * BATCH];
    unsigned short u = x[row * DIM + lane];
    sacc[tid] += __uint_as_float((unsigned)u << 16);
}

// ---------------------------------------------------------------------------
// Final: scores + raw layer-0 embeddings
// ---------------------------------------------------------------------------
__global__ void k_final(const float* __restrict__ sacc, const float* __restrict__ ue,
                        const float* __restrict__ ie, const int* __restrict__ users,
                        const int* __restrict__ pos, const int* __restrict__ neg,
                        float* __restrict__ out) {
    int tid = blockIdx.x * blockDim.x + threadIdx.x;
    int b = tid >> 6, lane = tid & 63;
    if (b >= BATCH) return;
    float ul = sacc[b * DIM + lane] * 0.25f;
    float pl = sacc[(BATCH + b) * DIM + lane] * 0.25f;
    float nl = sacc[(2 * BATCH + b) * DIM + lane] * 0.25f;
    float ps = ul * pl;
    float ns = ul * nl;
    for (int m = 1; m < 64; m <<= 1) {
        ps += __shfl_xor(ps, m, 64);
        ns += __shfl_xor(ns, m, 64);
    }
    if (lane == 0) {
        out[b] = ps;
        out[BATCH + b] = ns;
    }
    int u = users[b], p = pos[b], ng = neg[b];
    float* o = out + 2 * BATCH;
    o[b * DIM + lane]                   = ue[u * DIM + lane];
    o[BATCH * DIM + b * DIM + lane]     = ie[p * DIM + lane];
    o[2 * BATCH * DIM + b * DIM + lane] = ie[ng * DIM + lane];
}

// ---------------------------------------------------------------------------
extern "C" void kernel_launch(void* const* d_in, const int* in_sizes, int n_in,
                              void* d_out, int out_size, void* d_ws, size_t ws_size,
                              hipStream_t stream) {
    const float* user_emb = (const float*)d_in[0];
    const float* item_emb = (const float*)d_in[1];
    const float* adj_vals = (const float*)d_in[2];
    const int*   adj_rows = (const int*)d_in[3];
    const int*   adj_cols = (const int*)d_in[4];
    const int*   users    = (const int*)d_in[5];
    const int*   pos      = (const int*)d_in[6];
    const int*   neg      = (const int*)d_in[7];
    float* out = (float*)d_out;

    char* ws = (char*)d_ws;
    const size_t SZ_X = (size_t)N_TOTAL * DIM * 2;               // 19.2 MB (bf16)
    unsigned short* x_a = (unsigned short*)(ws);
    unsigned short* x_b = (unsigned short*)(ws + SZ_X);
    uint2* pairs    = (uint2*)(ws + 2 * SZ_X);
    uint2* bucketed = (uint2*)(ws + 2 * SZ_X + (size_t)NNZ * 8);
    char*  p3       = ws + 2 * SZ_X + 2 * (size_t)NNZ * 8;
    int*   row_ptr  = (int*)p3;                    // N_TOTAL + 1 (+pad)
    int*   btotal   = row_ptr + (N_TOTAL + 64);
    int*   bbase    = btotal + (NB + 64);          // NB + 1
    int*   myBase   = bbase + (NB + 64);           // PB * NB
    float* sacc     = (float*)(myBase + PB * NB + 64);

    const int TPB = 256;

    // 1) init x_a (bf16) + zero bucket totals
    k_init<<<(N_TOTAL * DIM / 4 + TPB - 1) / TPB, TPB, 0, stream>>>(user_emb, item_emb, x_a, btotal);
    // 2) CSR build: count -> scan -> bucket -> local scatter
    k_bcount<<<PB, TPB, 0, stream>>>(adj_rows, btotal, myBase);
    k_bscan<<<1, 64, 0, stream>>>(btotal, bbase, row_ptr);
    k_bucket<<<PB, TPB, 0, stream>>>(adj_rows, adj_cols, adj_vals, bbase, myBase, bucketed);
    k_csr<<<NB, 512, 0, stream>>>(bucketed, bbase, pairs, row_ptr);

    // 3) sacc = layer-0 rows (exact fp32 from inputs)
    k_gacc_init<<<(3 * BATCH * DIM) / TPB, TPB, 0, stream>>>(users, pos, neg, user_emb, item_emb, sacc);

    // 4) layers 1,2 full; layer 3 sampled-rows only (fused accumulate)
    const int SPMM_BLOCKS = (N_TOTAL * 64 + TPB - 1) / TPB;
    k_spmm<<<SPMM_BLOCKS, TPB, 0, stream>>>(row_ptr, pairs, x_a, x_b);
    k_gacc_add<<<(3 * BATCH * DIM) / TPB, TPB, 0, stream>>>(users, pos, neg, x_b, sacc);
    k_spmm<<<SPMM_BLOCKS, TPB, 0, stream>>>(row_ptr, pairs, x_b, x_a);
    k_gacc_add<<<(3 * BATCH * DIM) / TPB, TPB, 0, stream>>>(users, pos, neg, x_a, sacc);
    k_spmm_rows<<<(3 * BATCH * 64) / TPB, TPB, 0, stream>>>(row_ptr, pairs, x_a, users, pos, neg, sacc);

    // 5) final outputs
    k_final<<<(BATCH * DIM) / TPB, TPB, 0, stream>>>(sacc, user_emb, item_emb, users, pos, neg, out);
}